// Round 6
// baseline (3257.407 us; speedup 1.0000x reference)
//
#include <hip/hip_runtime.h>
#include <math.h>

#define B_   128
#define L_   256
#define DW_  100
#define DC_  30
#define HD_  200
#define NT_  18
#define SG   16    // batches per scan block (fills all 16 MFMA N-columns)
#define KP0  160   // padded K for layer-0 GEMM (130 -> 160)
#define KP1  416   // padded K for layer-1 GEMM (400 -> 416)

typedef _Float16 half8 __attribute__((ext_vector_type(8)));
typedef _Float16 half4 __attribute__((ext_vector_type(4)));
typedef float    f32x4 __attribute__((ext_vector_type(4)));

__device__ __forceinline__ float frcp_(float x) { return __builtin_amdgcn_rcpf(x); }
__device__ __forceinline__ float sigm_(float x) { return frcp_(1.0f + __expf(-x)); }
__device__ __forceinline__ float tanh_(float x) { return 1.0f - 2.0f * frcp_(1.0f + __expf(2.0f * x)); }

// barrier that does NOT drain vmcnt: LDS visibility only.
__device__ __forceinline__ void barrier_lgkm() {
    asm volatile("s_waitcnt lgkmcnt(0)" ::: "memory");
    __builtin_amdgcn_s_barrier();
    asm volatile("" ::: "memory");
}

// ---------------- seq_len rank sort -> perm (ascending), one block
__global__ __launch_bounds__(128) void k_sortperm(const int* __restrict__ seq_len,
                                                  int* __restrict__ perm) {
    __shared__ int s[B_];
    int i = threadIdx.x;
    s[i] = seq_len[i];
    __syncthreads();
    int key = s[i], r = 0;
    for (int j = 0; j < B_; j++) {
        int v = s[j];
        r += (v < key) || (v == key && j < i);
    }
    perm[r] = i;
}

// ---------------- embedding gather -> fp16 x (B*L, KP0), pads zeroed
__global__ void k_embed(const int* __restrict__ words, const int* __restrict__ caps,
                        const float* __restrict__ wemb, const float* __restrict__ cemb,
                        _Float16* __restrict__ x) {
    int pos = blockIdx.x;
    int w = words[pos], c = caps[pos];
    _Float16* xp = x + (size_t)pos * KP0;
    for (int t = threadIdx.x; t < KP0; t += blockDim.x) {
        float v = 0.f;
        if (t < DW_) v = wemb[(size_t)w * DW_ + t];
        else if (t < DW_ + DC_) v = cemb[(size_t)c * DC_ + (t - DW_)];
        xp[t] = (_Float16)v;
    }
}

// ---------------- W_ih prep: src (800,K) fp32 -> dst fp16 (1600, Kpad), col = colOff + 4*jh + g
__global__ void k_perm_ih16(const float* __restrict__ src, _Float16* __restrict__ dst,
                            int K, int Kpad, int colOff) {
    int i = blockIdx.x * blockDim.x + threadIdx.x;
    if (i >= 800 * Kpad) return;
    int r = i / Kpad, k = i - r * Kpad;
    int jh = r % 200, g = r / 200;
    int col = colOff + (jh << 2) + g;
    dst[(size_t)col * Kpad + k] = (k < K) ? (_Float16)src[(size_t)r * K + k] : (_Float16)0.f;
}

__global__ void k_bias_perm(const float* bi_f, const float* bh_f,
                            const float* bi_b, const float* bh_b, float* bias) {
    int j = blockIdx.x * blockDim.x + threadIdx.x;
    if (j >= 1600) return;
    int dir = j / 800, r = j - dir * 800;
    int col = dir * 800 + ((r % 200) << 2) + (r / 200);
    bias[col] = dir ? (bi_b[r] + bh_b[r]) : (bi_f[r] + bh_f[r]);
}

__global__ void k_wlog(const float* __restrict__ Wf, const float* __restrict__ bfv,
                       const float* __restrict__ Wb, const float* __restrict__ bbv,
                       float* __restrict__ wlog, float* __restrict__ blog) {
    int i = blockIdx.x * blockDim.x + threadIdx.x;
    if (i < NT_ * 400) {
        int t = i / 400, k = i - t * 400;
        wlog[i] = (k < HD_) ? Wf[t * HD_ + k] : Wb[t * HD_ + (k - HD_)];
    }
    if (i < NT_) blog[i] = bfv[i] + bbv[i];
}

// ---------------- MFMA fp16 GEMM: C(M,1600) = A(M,Kpad) @ Bt(1600,Kpad)^T + bias
__global__ __launch_bounds__(256) void k_gemm16(const _Float16* __restrict__ A,
                                                const _Float16* __restrict__ Bt,
                                                const float* __restrict__ bias,
                                                _Float16* __restrict__ C,
                                                int Kpad) {
    __shared__ __align__(16) _Float16 sA[128 * 40];
    __shared__ __align__(16) _Float16 sB[64 * 40];
    const int tid = threadIdx.x;
    const int w = tid >> 6, l = tid & 63, l15 = l & 15, lq = l >> 4;
    const int m0 = blockIdx.y * 128, n0 = blockIdx.x * 64;
    const int rw = (w >> 1) * 64, cw = (w & 1) * 32;
    f32x4 acc[4][2];
    #pragma unroll
    for (int i = 0; i < 4; i++)
        #pragma unroll
        for (int j = 0; j < 2; j++) acc[i][j] = f32x4{0.f, 0.f, 0.f, 0.f};

    for (int k0 = 0; k0 < Kpad; k0 += 32) {
        {
            int m = tid >> 1, c = (tid & 1) << 4;
            const _Float16* ap = A + (size_t)(m0 + m) * Kpad + k0 + c;
            *(half8*)&sA[m * 40 + c]     = *(const half8*)ap;
            *(half8*)&sA[m * 40 + c + 8] = *(const half8*)(ap + 8);
        }
        {
            int n = tid >> 2, k8 = (tid & 3) << 3;
            *(half8*)&sB[n * 40 + k8] = *(const half8*)&Bt[(size_t)(n0 + n) * Kpad + k0 + k8];
        }
        __syncthreads();
        half8 aF[4], bF[2];
        #pragma unroll
        for (int i = 0; i < 4; i++) aF[i] = *(const half8*)&sA[(rw + i * 16 + l15) * 40 + lq * 8];
        #pragma unroll
        for (int j = 0; j < 2; j++) bF[j] = *(const half8*)&sB[(cw + j * 16 + l15) * 40 + lq * 8];
        #pragma unroll
        for (int i = 0; i < 4; i++)
            #pragma unroll
            for (int j = 0; j < 2; j++)
                acc[i][j] = __builtin_amdgcn_mfma_f32_16x16x32_f16(aF[i], bF[j], acc[i][j], 0, 0, 0);
        __syncthreads();
    }
    #pragma unroll
    for (int j = 0; j < 2; j++) {
        int n = n0 + cw + j * 16 + l15;
        float bv = bias[n];
        #pragma unroll
        for (int i = 0; i < 4; i++) {
            int mrow = m0 + rw + i * 16 + lq * 4;
            #pragma unroll
            for (int r = 0; r < 4; r++)
                C[(size_t)(mrow + r) * 1600 + n] = (_Float16)(acc[i][j][r] + bv);
        }
    }
}

// ---------------- MFMA LSTM scan v12: SG=16 (v11 structure) + depth-2 gate prefetch (v9 pattern).
// D-layout (col=lane&15=batch, row=lq*4+reg, cols interleaved 4*jh+g): each lane's
// C[i] f32x4 IS the (i,f,g,o) set of cell (jh=(w*6+i)*4+lq, batch=l15) -> in-register
// nonlinearity, no LDS redistribution. Input gates double-buffered in registers:
// gc = step t, gn = step t+1; after consuming gc, gc<-gn and gn loads t+2.
__global__ __launch_bounds__(512) void k_scan12(const _Float16* __restrict__ gates,
                                                const float* __restrict__ Whh_f,
                                                const float* __restrict__ Whh_b,
                                                const int* __restrict__ seq_len,
                                                const int* __restrict__ perm,
                                                _Float16* __restrict__ hout, int ldH) {
    const int dir = blockIdx.x & 1;
    const int b0  = (blockIdx.x >> 1) * SG;
    const int tid = threadIdx.x;
    const int w   = tid >> 6;
    const int l   = tid & 63;
    const int l15 = l & 15;
    const int lq  = l >> 4;

    __shared__ __align__(16) _Float16 hA[2][16 * 232];   // ping-pong h state [p][batch*232+k]
    __shared__ __align__(16) _Float16 bEx[2 * 7 * 512];  // W-frags tiles 48,49 (waves 0,1)
    __shared__ int ssl[SG];
    __shared__ int spb[SG];

    const float* W = dir ? Whh_b : Whh_f;

    // resident W-fragments (A-operand layout): 6 register tiles + tiles 48/49 in LDS
    half8 Breg[6][7];
    #pragma unroll
    for (int i = 0; i < 6; i++) {
        int n  = (w * 6 + i) * 16 + l15;
        int jh = n >> 2, g = n & 3;
        const float* Wr = W + (size_t)(g * 200 + jh) * 200;
        #pragma unroll
        for (int kt = 0; kt < 7; kt++) {
            int k0 = kt * 32 + lq * 8;
            half8 f;
            #pragma unroll
            for (int j = 0; j < 8; j++) {
                int k = k0 + j;
                f[j] = (k < 200) ? (_Float16)Wr[k] : (_Float16)0.f;
            }
            Breg[i][kt] = f;
        }
    }
    if (w < 2) {
        int n  = (48 + w) * 16 + l15;
        int jh = n >> 2, g = n & 3;
        const float* Wr = W + (size_t)(g * 200 + jh) * 200;
        for (int kt = 0; kt < 7; kt++) {
            int k0 = kt * 32 + lq * 8;
            half8 f;
            for (int j = 0; j < 8; j++) {
                int k = k0 + j;
                f[j] = (k < 200) ? (_Float16)Wr[k] : (_Float16)0.f;
            }
            *(half8*)&bEx[(w * 7 + kt) * 512 + l * 8] = f;
        }
    }
    for (int i = tid; i < 2 * 16 * 232; i += 512) (&hA[0][0])[i] = (_Float16)0.f;
    if (tid < SG) {
        int ob = perm[b0 + tid];
        spb[tid] = ob;
        ssl[tid] = seq_len[ob];
    }

    __syncthreads();   // ssl/spb + zeroed hA + bEx visible

    int slmax = 0;
    #pragma unroll
    for (int j = 0; j < SG; j++) slmax = max(slmax, ssl[j]);

    // nonlinearity lane identity: cell (jh = (w*6+i)*4+lq, batch = l15) for each tile i
    const int sl_c = ssl[l15];
    const _Float16* gbase = gates + (size_t)spb[l15] * L_ * 1600 + dir * 800 + 4 * lq;

    // writeback lane identity: lane handles batch m_st, dwords u0+32k (h cols 2u..2u+1)
    const int m_st = tid >> 5;
    const int u0   = tid & 31;
    const int sl_st = ssl[m_st];
    _Float16* hout_b = hout + (size_t)spb[m_st] * L_ * ldH + dir * HD_;

    auto growOf = [&](int t) -> int {
        return dir ? ((t < sl_c) ? sl_c - 1 - t : t) : t;
    };

    float cs[7] = {0.f, 0.f, 0.f, 0.f, 0.f, 0.f, 0.f};
    const f32x4 Cz = {0.f, 0.f, 0.f, 0.f};

    // depth-2 register prefetch of input gates: gc = t, gn = t+1
    half4 gc[7], gn[7];
    {
        const _Float16* gR0 = gbase + (size_t)growOf(0) * 1600;
        const _Float16* gR1 = gbase + (size_t)growOf(1) * 1600;
        #pragma unroll
        for (int i = 0; i < 6; i++) {
            gc[i] = *(const half4*)(gR0 + 16 * (w * 6 + i));
            gn[i] = *(const half4*)(gR1 + 16 * (w * 6 + i));
        }
        if (w < 2) {
            gc[6] = *(const half4*)(gR0 + 16 * (48 + w));
            gn[6] = *(const half4*)(gR1 + 16 * (48 + w));
        }
    }

    for (int t = 0; t < slmax; t++) {
        const int p = t & 1;

        // coalesced writeback of h(t-1) from hA[p] (never drained in-loop)
        if (t > 0) {
            int tp = t - 1;
            bool live = tp < sl_st;
            int row = dir ? (live ? sl_st - 1 - tp : tp) : tp;
            _Float16* ho = hout_b + (size_t)row * ldH;
            #pragma unroll
            for (int k = 0; k < 4; k++) {
                int u = u0 + 32 * k;
                if (u < 100) {
                    unsigned int val = live ? *(const unsigned int*)&hA[p][m_st * 232 + 2 * u] : 0u;
                    *(unsigned int*)(ho + 2 * u) = val;
                }
            }
        }

        // MFMA: D = W @ h(t-1)^T  (A = W-frag, B = h-frag over 16 batches)
        f32x4 C[7];
        #pragma unroll
        for (int i = 0; i < 7; i++) C[i] = Cz;
        #pragma unroll
        for (int kt = 0; kt < 7; kt++) {
            half8 hF = *(const half8*)&hA[p][l15 * 232 + kt * 32 + lq * 8];
            #pragma unroll
            for (int i = 0; i < 6; i++)
                C[i] = __builtin_amdgcn_mfma_f32_16x16x32_f16(Breg[i][kt], hF, C[i], 0, 0, 0);
            if (w < 2) {
                half8 bF = *(const half8*)&bEx[(w * 7 + kt) * 512 + l * 8];
                C[6] = __builtin_amdgcn_mfma_f32_16x16x32_f16(bF, hF, C[6], 0, 0, 0);
            }
        }

        // in-register nonlinearity: C[i] + gc[i] = (i,f,g,o) of cell ((w*6+i)*4+lq, l15)
        #pragma unroll
        for (int i = 0; i < 6; i++) {
            float xi = C[i][0] + (float)gc[i][0];
            float xf = C[i][1] + (float)gc[i][1];
            float xg = C[i][2] + (float)gc[i][2];
            float xo = C[i][3] + (float)gc[i][3];
            float cn = sigm_(xf) * cs[i] + sigm_(xi) * tanh_(xg);
            cs[i] = cn;
            hA[1 - p][l15 * 232 + (w * 6 + i) * 4 + lq] = (_Float16)(sigm_(xo) * tanh_(cn));
        }
        if (w < 2) {
            float xi = C[6][0] + (float)gc[6][0];
            float xf = C[6][1] + (float)gc[6][1];
            float xg = C[6][2] + (float)gc[6][2];
            float xo = C[6][3] + (float)gc[6][3];
            float cn = sigm_(xf) * cs[6] + sigm_(xi) * tanh_(xg);
            cs[6] = cn;
            hA[1 - p][l15 * 232 + (48 + w) * 4 + lq] = (_Float16)(sigm_(xo) * tanh_(cn));
        }

        // rotate prefetch: gc <- gn (t+1), issue gn loads for t+2
        #pragma unroll
        for (int i = 0; i < 7; i++) gc[i] = gn[i];
        if (t + 2 < L_) {
            const _Float16* gR2 = gbase + (size_t)growOf(t + 2) * 1600;
            #pragma unroll
            for (int i = 0; i < 6; i++)
                gn[i] = *(const half4*)(gR2 + 16 * (w * 6 + i));
            if (w < 2) gn[6] = *(const half4*)(gR2 + 16 * (48 + w));
        }

        barrier_lgkm();   // LDS-only drain; vmcnt stays in flight
    }

    // epilogue 1: write back h(slmax-1) from hA[slmax&1]
    {
        int tp = slmax - 1;
        bool live = tp < sl_st;
        int row = dir ? (live ? sl_st - 1 - tp : tp) : tp;
        _Float16* ho = hout_b + (size_t)row * ldH;
        #pragma unroll
        for (int k = 0; k < 4; k++) {
            int u = u0 + 32 * k;
            if (u < 100) {
                unsigned int val = live ? *(const unsigned int*)&hA[slmax & 1][m_st * 232 + 2 * u] : 0u;
                *(unsigned int*)(ho + 2 * u) = val;
            }
        }
    }
    // epilogue 2: zero-fill rows [slmax, L)
    for (int tp = slmax; tp < L_; tp++) {
        _Float16* ho = hout_b + (size_t)tp * ldH;
        #pragma unroll
        for (int k = 0; k < 4; k++) {
            int u = u0 + 32 * k;
            if (u < 100) *(unsigned int*)(ho + 2 * u) = 0u;
        }
    }
}

// ---------------- logits: (B*L,18) = h1(B*L,400 fp16) @ wlog^T + blog
__global__ __launch_bounds__(256) void k_logits(const _Float16* __restrict__ h1,
                                                const float* __restrict__ wlog,
                                                const float* __restrict__ blog,
                                                float* __restrict__ logits) {
    __shared__ float sh[8][400];
    __shared__ float sw[NT_ * 400];
    int p0 = blockIdx.x * 8;
    for (int i = threadIdx.x; i < 8 * 400; i += 256)
        sh[i / 400][i % 400] = (float)h1[(size_t)p0 * 400 + i];
    for (int i = threadIdx.x; i < NT_ * 400; i += 256) sw[i] = wlog[i];
    __syncthreads();
    if (threadIdx.x < 8 * NT_) {
        int pi = threadIdx.x / NT_, tg = threadIdx.x % NT_;
        float a = blog[tg];
        #pragma unroll 4
        for (int k = 0; k < 400; k++) a += sh[pi][k] * sw[tg * 400 + k];
        logits[((size_t)(p0 + pi)) * NT_ + tg] = a;
    }
}

// ---------------- CRF NLL per batch row (54-lane-parallel LSE, single wave)
__global__ __launch_bounds__(64) void k_crf(const float* __restrict__ logits,
                                            const int* __restrict__ target,
                                            const int* __restrict__ seq_len,
                                            const float* __restrict__ trans,
                                            float* __restrict__ out) {
    int b = blockIdx.x, tid = threadIdx.x;
    __shared__ float alpha[NT_];
    int sl = seq_len[b];
    const float* lg = logits + (size_t)b * L_ * NT_;
    const int* tg = target + (size_t)b * L_;

    const bool act = tid < 54;
    const int c = tid / 18, j = tid - c * 18;

    float Tl[6];
    #pragma unroll
    for (int k = 0; k < 6; k++)
        Tl[k] = act ? trans[(6 * c + k) * NT_ + j] : 0.f;

    float gacc = 0.f;
    for (int t = tid; t < L_; t += 64) {
        if (t < sl) {
            gacc += lg[t * NT_ + tg[t]];
            if (t >= 1) gacc += trans[tg[t - 1] * NT_ + tg[t]];
        }
    }
    #pragma unroll
    for (int off = 32; off; off >>= 1) gacc += __shfl_down(gacc, off);
    float gold = __shfl(gacc, 0);

    if (tid < NT_) alpha[tid] = lg[tid];

    const int src1 = (c < 2) ? tid + 18 : tid - 36;
    const int src2 = (c == 0) ? tid + 36 : tid - 18;

    for (int t = 1; t < sl; t++) {
        float m = -1e30f, s = 0.f;
        if (act) {
            float v0 = alpha[6 * c + 0] + Tl[0];
            float v1 = alpha[6 * c + 1] + Tl[1];
            float v2 = alpha[6 * c + 2] + Tl[2];
            float v3 = alpha[6 * c + 3] + Tl[3];
            float v4 = alpha[6 * c + 4] + Tl[4];
            float v5 = alpha[6 * c + 5] + Tl[5];
            m = fmaxf(fmaxf(fmaxf(v0, v1), fmaxf(v2, v3)), fmaxf(v4, v5));
            s = __expf(v0 - m) + __expf(v1 - m) + __expf(v2 - m) +
                __expf(v3 - m) + __expf(v4 - m) + __expf(v5 - m);
        }
        float m1 = __shfl(m, src1), s1 = __shfl(s, src1);
        float m2 = __shfl(m, src2), s2 = __shfl(s, src2);
        if (act && c == 0) {
            float M = fmaxf(m, fmaxf(m1, m2));
            float S = s * __expf(m - M) + s1 * __expf(m1 - M) + s2 * __expf(m2 - M);
            alpha[j] = M + __logf(S) + lg[t * NT_ + j];
        }
    }
    if (tid == 0) {
        float mx = -1e30f;
        for (int i = 0; i < NT_; i++) mx = fmaxf(mx, alpha[i]);
        float s = 0.f;
        for (int i = 0; i < NT_; i++) s += __expf(alpha[i] - mx);
        out[b] = (mx + __logf(s)) - gold;
    }
}

extern "C" void kernel_launch(void* const* d_in, const int* in_sizes, int n_in,
                              void* d_out, int out_size, void* d_ws, size_t ws_size,
                              hipStream_t stream) {
    const int*   words  = (const int*)d_in[0];
    const int*   caps   = (const int*)d_in[1];
    const int*   seq    = (const int*)d_in[2];
    const int*   target = (const int*)d_in[3];
    const float* wemb   = (const float*)d_in[4];
    const float* cemb   = (const float*)d_in[5];
    const float* Wih0f  = (const float*)d_in[6];
    const float* Whh0f  = (const float*)d_in[7];
    const float* bih0f  = (const float*)d_in[8];
    const float* bhh0f  = (const float*)d_in[9];
    const float* Wih0b  = (const float*)d_in[10];
    const float* Whh0b  = (const float*)d_in[11];
    const float* bih0b  = (const float*)d_in[12];
    const float* bhh0b  = (const float*)d_in[13];
    const float* Wih1f  = (const float*)d_in[14];
    const float* Whh1f  = (const float*)d_in[15];
    const float* bih1f  = (const float*)d_in[16];
    const float* bhh1f  = (const float*)d_in[17];
    const float* Wih1b  = (const float*)d_in[18];
    const float* Whh1b  = (const float*)d_in[19];
    const float* bih1b  = (const float*)d_in[20];
    const float* bhh1b  = (const float*)d_in[21];
    const float* Wf     = (const float*)d_in[22];
    const float* bfv    = (const float*)d_in[23];
    const float* Wb     = (const float*)d_in[24];
    const float* bbv    = (const float*)d_in[25];
    const float* trans  = (const float*)d_in[26];

    char* base = (char*)d_ws;
    _Float16* gatesH = (_Float16*)(base + 0);                 // 104,857,600 B (32768x1600)
    _Float16* xbuf   = (_Float16*)(base + 104857600);         // 10,485,760 B (32768x160)
    _Float16* h0b    = (_Float16*)(base + 115343360);         // 27,262,976 B (32768x416)
    _Float16* h1b    = xbuf;  // 26,214,400 B needed; xbuf+h0 region dead by then
    float* logitsb   = (float*)(base + 142606336);            // 2,359,296 B
    _Float16* wihT0  = (_Float16*)(base + 144965632);         // 512,000 B (1600x160)
    _Float16* wihT1  = (_Float16*)(base + 145477632);         // 1,331,200 B (1600x416)
    float* bias0     = (float*)(base + 146808832);            // 6,400 B
    float* bias1     = (float*)(base + 146815232);            // 6,400 B
    float* wlog      = (float*)(base + 146821632);            // 28,800 B
    float* blog      = (float*)(base + 146850432);            // 128 B
    int*   permb     = (int*)(base + 146850560);              // 512 B

    // --- weight prep
    k_perm_ih16<<<(800 * KP0 + 255) / 256, 256, 0, stream>>>(Wih0f, wihT0, 130, KP0, 0);
    k_perm_ih16<<<(800 * KP0 + 255) / 256, 256, 0, stream>>>(Wih0b, wihT0, 130, KP0, 800);
    k_perm_ih16<<<(800 * KP1 + 255) / 256, 256, 0, stream>>>(Wih1f, wihT1, 400, KP1, 0);
    k_perm_ih16<<<(800 * KP1 + 255) / 256, 256, 0, stream>>>(Wih1b, wihT1, 400, KP1, 800);
    k_bias_perm<<<7, 256, 0, stream>>>(bih0f, bhh0f, bih0b, bhh0b, bias0);
    k_bias_perm<<<7, 256, 0, stream>>>(bih1f, bhh1f, bih1b, bhh1b, bias1);
    k_wlog<<<(NT_ * 400 + 255) / 256, 256, 0, stream>>>(Wf, bfv, Wb, bbv, wlog, blog);
    k_sortperm<<<1, 128, 0, stream>>>(seq, permb);

    // --- embeddings (fp16, padded)
    k_embed<<<B_ * L_, 128, 0, stream>>>(words, caps, wemb, cemb, xbuf);

    // zero h0 (its K-pad cols 400..415 must be 0 for the layer-1 GEMM)
    hipMemsetAsync(h0b, 0, (size_t)32768 * KP1 * sizeof(_Float16), stream);

    // --- layer 0
    k_gemm16<<<dim3(25, 256), 256, 0, stream>>>(xbuf, wihT0, bias0, gatesH, KP0);
    k_scan12<<<(B_ / SG) * 2, 512, 0, stream>>>(gatesH, Whh0f, Whh0b, seq, permb, h0b, KP1);

    // --- layer 1
    k_gemm16<<<dim3(25, 256), 256, 0, stream>>>(h0b, wihT1, bias1, gatesH, KP1);
    k_scan12<<<(B_ / SG) * 2, 512, 0, stream>>>(gatesH, Whh1f, Whh1b, seq, permb, h1b, 400);

    // --- logits + CRF
    k_logits<<<(B_ * L_) / 8, 256, 0, stream>>>(h1b, wlog, blog, logitsb);
    k_crf<<<B_, 64, 0, stream>>>(logitsb, target, seq, trans, (float*)d_out);
}

// Round 7
// 2807.898 us; speedup vs baseline: 1.1601x; 1.1601x over previous
//
#include <hip/hip_runtime.h>
#include <math.h>

#define B_   128
#define L_   256
#define DW_  100
#define DC_  30
#define HD_  200
#define NT_  18
#define SG   16    // batches per scan block (fills all 16 MFMA N-columns)
#define KP0  160   // padded K for layer-0 GEMM (130 -> 160)
#define KP1  416   // padded K for layer-1 GEMM (400 -> 416)
#define GPAD 808   // glds row pitch in halves (16B-aligned, bank-spread)

typedef _Float16 half8 __attribute__((ext_vector_type(8)));
typedef _Float16 half4 __attribute__((ext_vector_type(4)));
typedef float    f32x4 __attribute__((ext_vector_type(4)));

__device__ __forceinline__ float frcp_(float x) { return __builtin_amdgcn_rcpf(x); }
__device__ __forceinline__ float sigm_(float x) { return frcp_(1.0f + __expf(-x)); }
__device__ __forceinline__ float tanh_(float x) { return 1.0f - 2.0f * frcp_(1.0f + __expf(2.0f * x)); }

// barrier that does NOT drain vmcnt: LDS visibility only.
__device__ __forceinline__ void barrier_lgkm() {
    asm volatile("s_waitcnt lgkmcnt(0)" ::: "memory");
    __builtin_amdgcn_s_barrier();
    asm volatile("" ::: "memory");
}

// ---------------- seq_len rank sort -> perm (ascending), one block
__global__ __launch_bounds__(128) void k_sortperm(const int* __restrict__ seq_len,
                                                  int* __restrict__ perm) {
    __shared__ int s[B_];
    int i = threadIdx.x;
    s[i] = seq_len[i];
    __syncthreads();
    int key = s[i], r = 0;
    for (int j = 0; j < B_; j++) {
        int v = s[j];
        r += (v < key) || (v == key && j < i);
    }
    perm[r] = i;
}

// ---------------- embedding gather -> fp16 x (B*L, KP0), pads zeroed
__global__ void k_embed(const int* __restrict__ words, const int* __restrict__ caps,
                        const float* __restrict__ wemb, const float* __restrict__ cemb,
                        _Float16* __restrict__ x) {
    int pos = blockIdx.x;
    int w = words[pos], c = caps[pos];
    _Float16* xp = x + (size_t)pos * KP0;
    for (int t = threadIdx.x; t < KP0; t += blockDim.x) {
        float v = 0.f;
        if (t < DW_) v = wemb[(size_t)w * DW_ + t];
        else if (t < DW_ + DC_) v = cemb[(size_t)c * DC_ + (t - DW_)];
        xp[t] = (_Float16)v;
    }
}

// ---------------- W_ih prep: src (800,K) fp32 -> dst fp16 (1600, Kpad), col = colOff + 4*jh + g
__global__ void k_perm_ih16(const float* __restrict__ src, _Float16* __restrict__ dst,
                            int K, int Kpad, int colOff) {
    int i = blockIdx.x * blockDim.x + threadIdx.x;
    if (i >= 800 * Kpad) return;
    int r = i / Kpad, k = i - r * Kpad;
    int jh = r % 200, g = r / 200;
    int col = colOff + (jh << 2) + g;
    dst[(size_t)col * Kpad + k] = (k < K) ? (_Float16)src[(size_t)r * K + k] : (_Float16)0.f;
}

__global__ void k_bias_perm(const float* bi_f, const float* bh_f,
                            const float* bi_b, const float* bh_b, float* bias) {
    int j = blockIdx.x * blockDim.x + threadIdx.x;
    if (j >= 1600) return;
    int dir = j / 800, r = j - dir * 800;
    int col = dir * 800 + ((r % 200) << 2) + (r / 200);
    bias[col] = dir ? (bi_b[r] + bh_b[r]) : (bi_f[r] + bh_f[r]);
}

__global__ void k_wlog(const float* __restrict__ Wf, const float* __restrict__ bfv,
                       const float* __restrict__ Wb, const float* __restrict__ bbv,
                       float* __restrict__ wlog, float* __restrict__ blog) {
    int i = blockIdx.x * blockDim.x + threadIdx.x;
    if (i < NT_ * 400) {
        int t = i / 400, k = i - t * 400;
        wlog[i] = (k < HD_) ? Wf[t * HD_ + k] : Wb[t * HD_ + (k - HD_)];
    }
    if (i < NT_) blog[i] = bfv[i] + bbv[i];
}

// ---------------- MFMA fp16 GEMM: C(M,1600) = A(M,Kpad) @ Bt(1600,Kpad)^T + bias
__global__ __launch_bounds__(256) void k_gemm16(const _Float16* __restrict__ A,
                                                const _Float16* __restrict__ Bt,
                                                const float* __restrict__ bias,
                                                _Float16* __restrict__ C,
                                                int Kpad) {
    __shared__ __align__(16) _Float16 sA[128 * 40];
    __shared__ __align__(16) _Float16 sB[64 * 40];
    const int tid = threadIdx.x;
    const int w = tid >> 6, l = tid & 63, l15 = l & 15, lq = l >> 4;
    const int m0 = blockIdx.y * 128, n0 = blockIdx.x * 64;
    const int rw = (w >> 1) * 64, cw = (w & 1) * 32;
    f32x4 acc[4][2];
    #pragma unroll
    for (int i = 0; i < 4; i++)
        #pragma unroll
        for (int j = 0; j < 2; j++) acc[i][j] = f32x4{0.f, 0.f, 0.f, 0.f};

    for (int k0 = 0; k0 < Kpad; k0 += 32) {
        {
            int m = tid >> 1, c = (tid & 1) << 4;
            const _Float16* ap = A + (size_t)(m0 + m) * Kpad + k0 + c;
            *(half8*)&sA[m * 40 + c]     = *(const half8*)ap;
            *(half8*)&sA[m * 40 + c + 8] = *(const half8*)(ap + 8);
        }
        {
            int n = tid >> 2, k8 = (tid & 3) << 3;
            *(half8*)&sB[n * 40 + k8] = *(const half8*)&Bt[(size_t)(n0 + n) * Kpad + k0 + k8];
        }
        __syncthreads();
        half8 aF[4], bF[2];
        #pragma unroll
        for (int i = 0; i < 4; i++) aF[i] = *(const half8*)&sA[(rw + i * 16 + l15) * 40 + lq * 8];
        #pragma unroll
        for (int j = 0; j < 2; j++) bF[j] = *(const half8*)&sB[(cw + j * 16 + l15) * 40 + lq * 8];
        #pragma unroll
        for (int i = 0; i < 4; i++)
            #pragma unroll
            for (int j = 0; j < 2; j++)
                acc[i][j] = __builtin_amdgcn_mfma_f32_16x16x32_f16(aF[i], bF[j], acc[i][j], 0, 0, 0);
        __syncthreads();
    }
    #pragma unroll
    for (int j = 0; j < 2; j++) {
        int n = n0 + cw + j * 16 + l15;
        float bv = bias[n];
        #pragma unroll
        for (int i = 0; i < 4; i++) {
            int mrow = m0 + rw + i * 16 + lq * 4;
            #pragma unroll
            for (int r = 0; r < 4; r++)
                C[(size_t)(mrow + r) * 1600 + n] = (_Float16)(acc[i][j][r] + bv);
        }
    }
}

// ---------------- MFMA LSTM scan v13: SG=16 + COALESCED LDS-staged gates.
// v12's scattered per-cell gate gather (~900 x 32B transactions/block-step from
// only 16 CUs) was per-CU VMEM-concurrency-bound. v13 stages each step's 25.6KB
// (16 batches x 1600B) as 1600 coalesced half8 chunks (~200 cache lines),
// double-buffered in LDS; nonlinearity reads half4 from LDS.
__global__ __launch_bounds__(512) void k_scan13(const _Float16* __restrict__ gates,
                                                const float* __restrict__ Whh_f,
                                                const float* __restrict__ Whh_b,
                                                const int* __restrict__ seq_len,
                                                const int* __restrict__ perm,
                                                _Float16* __restrict__ hout, int ldH) {
    const int dir = blockIdx.x & 1;
    const int b0  = (blockIdx.x >> 1) * SG;
    const int tid = threadIdx.x;
    const int w   = tid >> 6;
    const int l   = tid & 63;
    const int l15 = l & 15;
    const int lq  = l >> 4;

    __shared__ __align__(16) _Float16 hA[2][16 * 232];    // ping-pong h state [p][batch*232+k]
    __shared__ __align__(16) _Float16 bEx[2 * 7 * 512];   // W-frags tiles 48,49 (waves 0,1)
    __shared__ __align__(16) _Float16 glds[2][16 * GPAD]; // staged gates [buf][batch*GPAD + col]
    __shared__ int ssl[SG];
    __shared__ int spb[SG];

    const float* W = dir ? Whh_b : Whh_f;

    // resident W-fragments (A-operand layout): 6 register tiles + tiles 48/49 in LDS
    half8 Breg[6][7];
    #pragma unroll
    for (int i = 0; i < 6; i++) {
        int n  = (w * 6 + i) * 16 + l15;
        int jh = n >> 2, g = n & 3;
        const float* Wr = W + (size_t)(g * 200 + jh) * 200;
        #pragma unroll
        for (int kt = 0; kt < 7; kt++) {
            int k0 = kt * 32 + lq * 8;
            half8 f;
            #pragma unroll
            for (int j = 0; j < 8; j++) {
                int k = k0 + j;
                f[j] = (k < 200) ? (_Float16)Wr[k] : (_Float16)0.f;
            }
            Breg[i][kt] = f;
        }
    }
    if (w < 2) {
        int n  = (48 + w) * 16 + l15;
        int jh = n >> 2, g = n & 3;
        const float* Wr = W + (size_t)(g * 200 + jh) * 200;
        for (int kt = 0; kt < 7; kt++) {
            int k0 = kt * 32 + lq * 8;
            half8 f;
            for (int j = 0; j < 8; j++) {
                int k = k0 + j;
                f[j] = (k < 200) ? (_Float16)Wr[k] : (_Float16)0.f;
            }
            *(half8*)&bEx[(w * 7 + kt) * 512 + l * 8] = f;
        }
    }
    for (int i = tid; i < 2 * 16 * 232; i += 512) (&hA[0][0])[i] = (_Float16)0.f;
    if (tid < SG) {
        int ob = perm[b0 + tid];
        spb[tid] = ob;
        ssl[tid] = seq_len[ob];
    }

    __syncthreads();   // ssl/spb + zeroed hA + bEx visible

    int slmax = 0;
    #pragma unroll
    for (int j = 0; j < SG; j++) slmax = max(slmax, ssl[j]);

    // staging identity: chunk j = tid + 512r covers 1600 x 16B; batch = j/100, slot = j%100
    const _Float16* sptr[4];
    int sdst[4], sseq[4];
    bool sval[4];
    #pragma unroll
    for (int r = 0; r < 4; r++) {
        int j = tid + r * 512;
        sval[r] = j < 1600;
        int bb = sval[r] ? (j / 100) : 0;
        int slot = j - bb * 100;
        sseq[r] = ssl[bb];
        sdst[r] = bb * GPAD + slot * 8;
        sptr[r] = gates + (size_t)spb[bb] * L_ * 1600 + dir * 800 + slot * 8;
    }

    // writeback lane identity: lane handles batch m_st, dwords u0+32k (h cols 2u..2u+1)
    const int m_st = tid >> 5;
    const int u0   = tid & 31;
    const int sl_st = ssl[m_st];
    _Float16* hout_b = hout + (size_t)spb[m_st] * L_ * ldH + dir * HD_;

    float cs[7] = {0.f, 0.f, 0.f, 0.f, 0.f, 0.f, 0.f};
    const f32x4 Cz = {0.f, 0.f, 0.f, 0.f};

    // prologue: stage gates for t=0 into glds[0]
    {
        half8 s0[4];
        #pragma unroll
        for (int r = 0; r < 4; r++) {
            if (sval[r]) {
                int sl = sseq[r];
                int row = dir ? ((0 < sl) ? sl - 1 : 0) : 0;
                s0[r] = *(const half8*)(sptr[r] + (size_t)row * 1600);
            }
        }
        #pragma unroll
        for (int r = 0; r < 4; r++)
            if (sval[r]) *(half8*)&glds[0][sdst[r]] = s0[r];
    }
    barrier_lgkm();

    for (int t = 0; t < slmax; t++) {
        const int p = t & 1;

        // 1. coalesced writeback of h(t-1) from hA[p] (never drained in-loop)
        if (t > 0) {
            int tp = t - 1;
            bool live = tp < sl_st;
            int row = dir ? (live ? sl_st - 1 - tp : tp) : tp;
            _Float16* ho = hout_b + (size_t)row * ldH;
            #pragma unroll
            for (int k = 0; k < 4; k++) {
                int u = u0 + 32 * k;
                if (u < 100) {
                    unsigned int val = live ? *(const unsigned int*)&hA[p][m_st * 232 + 2 * u] : 0u;
                    *(unsigned int*)(ho + 2 * u) = val;
                }
            }
        }

        // 2. issue coalesced staged loads for t+1 (consumed after MFMA+nonlin)
        half8 sreg[4];
        const bool doStg = (t + 1) < slmax;
        if (doStg) {
            int tn = t + 1;
            #pragma unroll
            for (int r = 0; r < 4; r++) {
                if (sval[r]) {
                    int sl = sseq[r];
                    int row = dir ? ((tn < sl) ? sl - 1 - tn : tn) : tn;
                    sreg[r] = *(const half8*)(sptr[r] + (size_t)row * 1600);
                }
            }
        }

        // 3. MFMA: D = W @ h(t-1)^T  (A = W-frag, B = h-frag over 16 batches)
        f32x4 C[7];
        #pragma unroll
        for (int i = 0; i < 7; i++) C[i] = Cz;
        #pragma unroll
        for (int kt = 0; kt < 7; kt++) {
            half8 hF = *(const half8*)&hA[p][l15 * 232 + kt * 32 + lq * 8];
            #pragma unroll
            for (int i = 0; i < 6; i++)
                C[i] = __builtin_amdgcn_mfma_f32_16x16x32_f16(Breg[i][kt], hF, C[i], 0, 0, 0);
            if (w < 2) {
                half8 bF = *(const half8*)&bEx[(w * 7 + kt) * 512 + l * 8];
                C[6] = __builtin_amdgcn_mfma_f32_16x16x32_f16(bF, hF, C[6], 0, 0, 0);
            }
        }

        // 4. in-register nonlinearity; input gates from glds[p] (half4 ds_read)
        #pragma unroll
        for (int i = 0; i < 6; i++) {
            half4 g4 = *(const half4*)&glds[p][l15 * GPAD + 16 * (w * 6 + i) + 4 * lq];
            float xi = C[i][0] + (float)g4[0];
            float xf = C[i][1] + (float)g4[1];
            float xg = C[i][2] + (float)g4[2];
            float xo = C[i][3] + (float)g4[3];
            float cn = sigm_(xf) * cs[i] + sigm_(xi) * tanh_(xg);
            cs[i] = cn;
            hA[1 - p][l15 * 232 + (w * 6 + i) * 4 + lq] = (_Float16)(sigm_(xo) * tanh_(cn));
        }
        if (w < 2) {
            half4 g4 = *(const half4*)&glds[p][l15 * GPAD + 16 * (48 + w) + 4 * lq];
            float xi = C[6][0] + (float)g4[0];
            float xf = C[6][1] + (float)g4[1];
            float xg = C[6][2] + (float)g4[2];
            float xo = C[6][3] + (float)g4[3];
            float cn = sigm_(xf) * cs[6] + sigm_(xi) * tanh_(xg);
            cs[6] = cn;
            hA[1 - p][l15 * 232 + (48 + w) * 4 + lq] = (_Float16)(sigm_(xo) * tanh_(cn));
        }

        // 5. commit staged gates for t+1 (compiler inserts the vmcnt wait here)
        if (doStg) {
            #pragma unroll
            for (int r = 0; r < 4; r++)
                if (sval[r]) *(half8*)&glds[1 - p][sdst[r]] = sreg[r];
        }

        barrier_lgkm();   // LDS-only drain; vmcnt stays in flight
    }

    // epilogue 1: write back h(slmax-1) from hA[slmax&1]
    {
        int tp = slmax - 1;
        bool live = tp < sl_st;
        int row = dir ? (live ? sl_st - 1 - tp : tp) : tp;
        _Float16* ho = hout_b + (size_t)row * ldH;
        #pragma unroll
        for (int k = 0; k < 4; k++) {
            int u = u0 + 32 * k;
            if (u < 100) {
                unsigned int val = live ? *(const unsigned int*)&hA[slmax & 1][m_st * 232 + 2 * u] : 0u;
                *(unsigned int*)(ho + 2 * u) = val;
            }
        }
    }
    // epilogue 2: zero-fill rows [slmax, L)
    for (int tp = slmax; tp < L_; tp++) {
        _Float16* ho = hout_b + (size_t)tp * ldH;
        #pragma unroll
        for (int k = 0; k < 4; k++) {
            int u = u0 + 32 * k;
            if (u < 100) *(unsigned int*)(ho + 2 * u) = 0u;
        }
    }
}

// ---------------- logits: (B*L,18) = h1(B*L,400 fp16) @ wlog^T + blog
__global__ __launch_bounds__(256) void k_logits(const _Float16* __restrict__ h1,
                                                const float* __restrict__ wlog,
                                                const float* __restrict__ blog,
                                                float* __restrict__ logits) {
    __shared__ float sh[8][400];
    __shared__ float sw[NT_ * 400];
    int p0 = blockIdx.x * 8;
    for (int i = threadIdx.x; i < 8 * 400; i += 256)
        sh[i / 400][i % 400] = (float)h1[(size_t)p0 * 400 + i];
    for (int i = threadIdx.x; i < NT_ * 400; i += 256) sw[i] = wlog[i];
    __syncthreads();
    if (threadIdx.x < 8 * NT_) {
        int pi = threadIdx.x / NT_, tg = threadIdx.x % NT_;
        float a = blog[tg];
        #pragma unroll 4
        for (int k = 0; k < 400; k++) a += sh[pi][k] * sw[tg * 400 + k];
        logits[((size_t)(p0 + pi)) * NT_ + tg] = a;
    }
}

// ---------------- CRF NLL per batch row (54-lane-parallel LSE, single wave)
__global__ __launch_bounds__(64) void k_crf(const float* __restrict__ logits,
                                            const int* __restrict__ target,
                                            const int* __restrict__ seq_len,
                                            const float* __restrict__ trans,
                                            float* __restrict__ out) {
    int b = blockIdx.x, tid = threadIdx.x;
    __shared__ float alpha[NT_];
    int sl = seq_len[b];
    const float* lg = logits + (size_t)b * L_ * NT_;
    const int* tg = target + (size_t)b * L_;

    const bool act = tid < 54;
    const int c = tid / 18, j = tid - c * 18;

    float Tl[6];
    #pragma unroll
    for (int k = 0; k < 6; k++)
        Tl[k] = act ? trans[(6 * c + k) * NT_ + j] : 0.f;

    float gacc = 0.f;
    for (int t = tid; t < L_; t += 64) {
        if (t < sl) {
            gacc += lg[t * NT_ + tg[t]];
            if (t >= 1) gacc += trans[tg[t - 1] * NT_ + tg[t]];
        }
    }
    #pragma unroll
    for (int off = 32; off; off >>= 1) gacc += __shfl_down(gacc, off);
    float gold = __shfl(gacc, 0);

    if (tid < NT_) alpha[tid] = lg[tid];

    const int src1 = (c < 2) ? tid + 18 : tid - 36;
    const int src2 = (c == 0) ? tid + 36 : tid - 18;

    for (int t = 1; t < sl; t++) {
        float m = -1e30f, s = 0.f;
        if (act) {
            float v0 = alpha[6 * c + 0] + Tl[0];
            float v1 = alpha[6 * c + 1] + Tl[1];
            float v2 = alpha[6 * c + 2] + Tl[2];
            float v3 = alpha[6 * c + 3] + Tl[3];
            float v4 = alpha[6 * c + 4] + Tl[4];
            float v5 = alpha[6 * c + 5] + Tl[5];
            m = fmaxf(fmaxf(fmaxf(v0, v1), fmaxf(v2, v3)), fmaxf(v4, v5));
            s = __expf(v0 - m) + __expf(v1 - m) + __expf(v2 - m) +
                __expf(v3 - m) + __expf(v4 - m) + __expf(v5 - m);
        }
        float m1 = __shfl(m, src1), s1 = __shfl(s, src1);
        float m2 = __shfl(m, src2), s2 = __shfl(s, src2);
        if (act && c == 0) {
            float M = fmaxf(m, fmaxf(m1, m2));
            float S = s * __expf(m - M) + s1 * __expf(m1 - M) + s2 * __expf(m2 - M);
            alpha[j] = M + __logf(S) + lg[t * NT_ + j];
        }
    }
    if (tid == 0) {
        float mx = -1e30f;
        for (int i = 0; i < NT_; i++) mx = fmaxf(mx, alpha[i]);
        float s = 0.f;
        for (int i = 0; i < NT_; i++) s += __expf(alpha[i] - mx);
        out[b] = (mx + __logf(s)) - gold;
    }
}

extern "C" void kernel_launch(void* const* d_in, const int* in_sizes, int n_in,
                              void* d_out, int out_size, void* d_ws, size_t ws_size,
                              hipStream_t stream) {
    const int*   words  = (const int*)d_in[0];
    const int*   caps   = (const int*)d_in[1];
    const int*   seq    = (const int*)d_in[2];
    const int*   target = (const int*)d_in[3];
    const float* wemb   = (const float*)d_in[4];
    const float* cemb   = (const float*)d_in[5];
    const float* Wih0f  = (const float*)d_in[6];
    const float* Whh0f  = (const float*)d_in[7];
    const float* bih0f  = (const float*)d_in[8];
    const float* bhh0f  = (const float*)d_in[9];
    const float* Wih0b  = (const float*)d_in[10];
    const float* Whh0b  = (const float*)d_in[11];
    const float* bih0b  = (const float*)d_in[12];
    const float* bhh0b  = (const float*)d_in[13];
    const float* Wih1f  = (const float*)d_in[14];
    const float* Whh1f  = (const float*)d_in[15];
    const float* bih1f  = (const float*)d_in[16];
    const float* bhh1f  = (const float*)d_in[17];
    const float* Wih1b  = (const float*)d_in[18];
    const float* Whh1b  = (const float*)d_in[19];
    const float* bih1b  = (const float*)d_in[20];
    const float* bhh1b  = (const float*)d_in[21];
    const float* Wf     = (const float*)d_in[22];
    const float* bfv    = (const float*)d_in[23];
    const float* Wb     = (const float*)d_in[24];
    const float* bbv    = (const float*)d_in[25];
    const float* trans  = (const float*)d_in[26];

    char* base = (char*)d_ws;
    _Float16* gatesH = (_Float16*)(base + 0);                 // 104,857,600 B (32768x1600)
    _Float16* xbuf   = (_Float16*)(base + 104857600);         // 10,485,760 B (32768x160)
    _Float16* h0b    = (_Float16*)(base + 115343360);         // 27,262,976 B (32768x416)
    _Float16* h1b    = xbuf;  // 26,214,400 B needed; xbuf+h0 region dead by then
    float* logitsb   = (float*)(base + 142606336);            // 2,359,296 B
    _Float16* wihT0  = (_Float16*)(base + 144965632);         // 512,000 B (1600x160)
    _Float16* wihT1  = (_Float16*)(base + 145477632);         // 1,331,200 B (1600x416)
    float* bias0     = (float*)(base + 146808832);            // 6,400 B
    float* bias1     = (float*)(base + 146815232);            // 6,400 B
    float* wlog      = (float*)(base + 146821632);            // 28,800 B
    float* blog      = (float*)(base + 146850432);            // 128 B
    int*   permb     = (int*)(base + 146850560);              // 512 B

    // --- weight prep
    k_perm_ih16<<<(800 * KP0 + 255) / 256, 256, 0, stream>>>(Wih0f, wihT0, 130, KP0, 0);
    k_perm_ih16<<<(800 * KP0 + 255) / 256, 256, 0, stream>>>(Wih0b, wihT0, 130, KP0, 800);
    k_perm_ih16<<<(800 * KP1 + 255) / 256, 256, 0, stream>>>(Wih1f, wihT1, 400, KP1, 0);
    k_perm_ih16<<<(800 * KP1 + 255) / 256, 256, 0, stream>>>(Wih1b, wihT1, 400, KP1, 800);
    k_bias_perm<<<7, 256, 0, stream>>>(bih0f, bhh0f, bih0b, bhh0b, bias0);
    k_bias_perm<<<7, 256, 0, stream>>>(bih1f, bhh1f, bih1b, bhh1b, bias1);
    k_wlog<<<(NT_ * 400 + 255) / 256, 256, 0, stream>>>(Wf, bfv, Wb, bbv, wlog, blog);
    k_sortperm<<<1, 128, 0, stream>>>(seq, permb);

    // --- embeddings (fp16, padded)
    k_embed<<<B_ * L_, 128, 0, stream>>>(words, caps, wemb, cemb, xbuf);

    // zero h0 (its K-pad cols 400..415 must be 0 for the layer-1 GEMM)
    hipMemsetAsync(h0b, 0, (size_t)32768 * KP1 * sizeof(_Float16), stream);

    // --- layer 0
    k_gemm16<<<dim3(25, 256), 256, 0, stream>>>(xbuf, wihT0, bias0, gatesH, KP0);
    k_scan13<<<(B_ / SG) * 2, 512, 0, stream>>>(gatesH, Whh0f, Whh0b, seq, permb, h0b, KP1);

    // --- layer 1
    k_gemm16<<<dim3(25, 256), 256, 0, stream>>>(h0b, wihT1, bias1, gatesH, KP1);
    k_scan13<<<(B_ / SG) * 2, 512, 0, stream>>>(gatesH, Whh1f, Whh1b, seq, permb, h1b, 400);

    // --- logits + CRF
    k_logits<<<(B_ * L_) / 8, 256, 0, stream>>>(h1b, wlog, blog, logitsb);
    k_crf<<<B_, 64, 0, stream>>>(logitsb, target, seq, trans, (float*)d_out);
}

// Round 8
// 1359.974 us; speedup vs baseline: 2.3952x; 2.0647x over previous
//
#include <hip/hip_runtime.h>
#include <math.h>

#define B_   128
#define L_   256
#define DW_  100
#define DC_  30
#define HD_  200
#define NT_  18
#define SG   4     // batches per scan block (v10 proven config)
#define KP0  160   // padded K for layer-0 GEMM (130 -> 160)
#define KP1  416   // padded K for layer-1 GEMM (400 -> 416)
#define WLP  424   // wlB pitch in halves (16B-aligned, 8-bank spread)

typedef _Float16 half8 __attribute__((ext_vector_type(8)));
typedef _Float16 half4 __attribute__((ext_vector_type(4)));
typedef float    f32x4 __attribute__((ext_vector_type(4)));

__device__ __forceinline__ float frcp_(float x) { return __builtin_amdgcn_rcpf(x); }
__device__ __forceinline__ float sigm_(float x) { return frcp_(1.0f + __expf(-x)); }
__device__ __forceinline__ float tanh_(float x) { return 1.0f - 2.0f * frcp_(1.0f + __expf(2.0f * x)); }

// barrier that does NOT drain vmcnt: LDS visibility only.
__device__ __forceinline__ void barrier_lgkm() {
    asm volatile("s_waitcnt lgkmcnt(0)" ::: "memory");
    __builtin_amdgcn_s_barrier();
    asm volatile("" ::: "memory");
}

// ---------------- seq_len rank sort -> perm (ascending), one block
__global__ __launch_bounds__(128) void k_sortperm(const int* __restrict__ seq_len,
                                                  int* __restrict__ perm) {
    __shared__ int s[B_];
    int i = threadIdx.x;
    s[i] = seq_len[i];
    __syncthreads();
    int key = s[i], r = 0;
    for (int j = 0; j < B_; j++) {
        int v = s[j];
        r += (v < key) || (v == key && j < i);
    }
    perm[r] = i;
}

// ---------------- embedding gather -> fp16 x (B*L, KP0), pads zeroed
__global__ void k_embed(const int* __restrict__ words, const int* __restrict__ caps,
                        const float* __restrict__ wemb, const float* __restrict__ cemb,
                        _Float16* __restrict__ x) {
    int pos = blockIdx.x;
    int w = words[pos], c = caps[pos];
    _Float16* xp = x + (size_t)pos * KP0;
    for (int t = threadIdx.x; t < KP0; t += blockDim.x) {
        float v = 0.f;
        if (t < DW_) v = wemb[(size_t)w * DW_ + t];
        else if (t < DW_ + DC_) v = cemb[(size_t)c * DC_ + (t - DW_)];
        xp[t] = (_Float16)v;
    }
}

// ---------------- W_ih prep: src (800,K) fp32 -> dst fp16 (1600, Kpad), col = colOff + 4*jh + g
__global__ void k_perm_ih16(const float* __restrict__ src, _Float16* __restrict__ dst,
                            int K, int Kpad, int colOff) {
    int i = blockIdx.x * blockDim.x + threadIdx.x;
    if (i >= 800 * Kpad) return;
    int r = i / Kpad, k = i - r * Kpad;
    int jh = r % 200, g = r / 200;
    int col = colOff + (jh << 2) + g;
    dst[(size_t)col * Kpad + k] = (k < K) ? (_Float16)src[(size_t)r * K + k] : (_Float16)0.f;
}

__global__ void k_bias_perm(const float* bi_f, const float* bh_f,
                            const float* bi_b, const float* bh_b, float* bias) {
    int j = blockIdx.x * blockDim.x + threadIdx.x;
    if (j >= 1600) return;
    int dir = j / 800, r = j - dir * 800;
    int col = dir * 800 + ((r % 200) << 2) + (r / 200);
    bias[col] = dir ? (bi_b[r] + bh_b[r]) : (bi_f[r] + bh_f[r]);
}

// ---------------- W_log prep: wlB fp16 [32][WLP], row n = [Wf_n | Wb_n], zero-padded
__global__ void k_wlog(const float* __restrict__ Wf, const float* __restrict__ bfv,
                       const float* __restrict__ Wb, const float* __restrict__ bbv,
                       _Float16* __restrict__ wlB, float* __restrict__ blog) {
    int i = blockIdx.x * blockDim.x + threadIdx.x;
    if (i < 32 * WLP) {
        int n = i / WLP, k = i - n * WLP;
        float v = 0.f;
        if (n < NT_ && k < 400) v = (k < HD_) ? Wf[n * HD_ + k] : Wb[n * HD_ + (k - HD_)];
        wlB[i] = (_Float16)v;
    }
    if (i < NT_) blog[i] = bfv[i] + bbv[i];
}

// ---------------- MFMA fp16 GEMM: C(M,1600) = A(M,Kpad) @ Bt(1600,Kpad)^T + bias
__global__ __launch_bounds__(256) void k_gemm16(const _Float16* __restrict__ A,
                                                const _Float16* __restrict__ Bt,
                                                const float* __restrict__ bias,
                                                _Float16* __restrict__ C,
                                                int Kpad) {
    __shared__ __align__(16) _Float16 sA[128 * 40];
    __shared__ __align__(16) _Float16 sB[64 * 40];
    const int tid = threadIdx.x;
    const int w = tid >> 6, l = tid & 63, l15 = l & 15, lq = l >> 4;
    const int m0 = blockIdx.y * 128, n0 = blockIdx.x * 64;
    const int rw = (w >> 1) * 64, cw = (w & 1) * 32;
    f32x4 acc[4][2];
    #pragma unroll
    for (int i = 0; i < 4; i++)
        #pragma unroll
        for (int j = 0; j < 2; j++) acc[i][j] = f32x4{0.f, 0.f, 0.f, 0.f};

    for (int k0 = 0; k0 < Kpad; k0 += 32) {
        {
            int m = tid >> 1, c = (tid & 1) << 4;
            const _Float16* ap = A + (size_t)(m0 + m) * Kpad + k0 + c;
            *(half8*)&sA[m * 40 + c]     = *(const half8*)ap;
            *(half8*)&sA[m * 40 + c + 8] = *(const half8*)(ap + 8);
        }
        {
            int n = tid >> 2, k8 = (tid & 3) << 3;
            *(half8*)&sB[n * 40 + k8] = *(const half8*)&Bt[(size_t)(n0 + n) * Kpad + k0 + k8];
        }
        __syncthreads();
        half8 aF[4], bF[2];
        #pragma unroll
        for (int i = 0; i < 4; i++) aF[i] = *(const half8*)&sA[(rw + i * 16 + l15) * 40 + lq * 8];
        #pragma unroll
        for (int j = 0; j < 2; j++) bF[j] = *(const half8*)&sB[(cw + j * 16 + l15) * 40 + lq * 8];
        #pragma unroll
        for (int i = 0; i < 4; i++)
            #pragma unroll
            for (int j = 0; j < 2; j++)
                acc[i][j] = __builtin_amdgcn_mfma_f32_16x16x32_f16(aF[i], bF[j], acc[i][j], 0, 0, 0);
        __syncthreads();
    }
    #pragma unroll
    for (int j = 0; j < 2; j++) {
        int n = n0 + cw + j * 16 + l15;
        float bv = bias[n];
        #pragma unroll
        for (int i = 0; i < 4; i++) {
            int mrow = m0 + rw + i * 16 + lq * 4;
            #pragma unroll
            for (int r = 0; r < 4; r++)
                C[(size_t)(mrow + r) * 1600 + n] = (_Float16)(acc[i][j][r] + bv);
        }
    }
}

// ---------------- MFMA LSTM scan v10 (measured best: 449 us/dispatch @ SG=4)
__global__ __launch_bounds__(512) void k_scan10(const _Float16* __restrict__ gates,
                                                const float* __restrict__ Whh_f,
                                                const float* __restrict__ Whh_b,
                                                const int* __restrict__ seq_len,
                                                const int* __restrict__ perm,
                                                _Float16* __restrict__ hout, int ldH) {
    const int dir = blockIdx.x & 1;
    const int b0  = (blockIdx.x >> 1) * SG;
    const int tid = threadIdx.x;
    const int w   = tid >> 6;
    const int l   = tid & 63;
    const int l15 = l & 15;
    const int lq  = l >> 4;

    __shared__ __align__(16) _Float16 hA[2][16 * 232];   // ping-pong h state [p][m*232+k]
    __shared__ __align__(16) _Float16 bEx[2 * 7 * 512];  // W-frags tiles 48,49 (waves 0,1)
    __shared__ __align__(16) float    gD[8 * 448];       // per-wave gate sums [w*448 + cell*4 + g]
    __shared__ int ssl[SG];
    __shared__ int spb[SG];

    const float* W = dir ? Whh_b : Whh_f;
    const int nT = (w < 2) ? 7 : 6;
    const int nCell = nT * 16;          // cells owned by this wave

    // resident W-fragments (A-operand layout): 6 register tiles + tiles 48/49 in LDS
    half8 Breg[6][7];
    #pragma unroll
    for (int i = 0; i < 6; i++) {
        int n  = (w * 6 + i) * 16 + l15;
        int jh = n >> 2, g = n & 3;
        const float* Wr = W + (size_t)(g * 200 + jh) * 200;
        #pragma unroll
        for (int kt = 0; kt < 7; kt++) {
            int k0 = kt * 32 + lq * 8;
            half8 f;
            #pragma unroll
            for (int j = 0; j < 8; j++) {
                int k = k0 + j;
                f[j] = (k < 200) ? (_Float16)Wr[k] : (_Float16)0.f;
            }
            Breg[i][kt] = f;
        }
    }
    if (w < 2) {
        int n  = (48 + w) * 16 + l15;
        int jh = n >> 2, g = n & 3;
        const float* Wr = W + (size_t)(g * 200 + jh) * 200;
        for (int kt = 0; kt < 7; kt++) {
            int k0 = kt * 32 + lq * 8;
            half8 f;
            for (int j = 0; j < 8; j++) {
                int k = k0 + j;
                f[j] = (k < 200) ? (_Float16)Wr[k] : (_Float16)0.f;
            }
            *(half8*)&bEx[(w * 7 + kt) * 512 + l * 8] = f;
        }
    }
    for (int i = tid; i < 2 * 16 * 232; i += 512) (&hA[0][0])[i] = (_Float16)0.f;
    if (tid < SG) {
        int ob = perm[b0 + tid];
        spb[tid] = ob;
        ssl[tid] = seq_len[ob];
    }

    // writeback lane identity: lane v writes 4B of h row m_st
    const int  v    = tid;
    const bool stv  = v < 400;
    const int  m_st = v / 100;
    const int  u_st = v - m_st * 100;

    // nonlinearity cell identities: lane handles cells cA = l, cB = l + 64 (wave-local)
    const int cA = l;
    const int iA = cA >> 4, qA = (cA >> 2) & 3, mA = cA & 3;
    const int tgA = (iA < 6) ? (w * 6 + iA) : (48 + w);
    const int hcA = tgA * 4 + qA;
    const int cB = l + 64;
    const int iB = cB >> 4, qB = (cB >> 2) & 3, mB = cB & 3;
    const bool vB = cB < nCell;
    const int tgB = (iB < 6) ? (w * 6 + iB) : (48 + w);
    const int hcB = tgB * 4 + qB;
    float csA = 0.f, csB = 0.f;

    __syncthreads();   // ssl/spb + zeroed hA + bEx visible

    const int slmax = max(max(ssl[0], ssl[1]), max(ssl[2], ssl[3]));

    // per-cell gate pointers and seq lens (recurrence-independent addresses)
    const int slA = ssl[mA];
    const int slB = ssl[mB];
    const int slb_st = stv ? ssl[m_st] : 0;
    const _Float16* gA_base = gates + ((size_t)spb[mA] * L_) * 1600 + dir * 800 + 4 * hcA;
    const _Float16* gB_base = gates + ((size_t)spb[mB] * L_) * 1600 + dir * 800 + 4 * hcB;
    _Float16* hout_base = stv ? (hout + (size_t)spb[m_st] * L_ * ldH + dir * HD_ + 2 * u_st)
                              : hout;

    auto rowOf = [&](int t, int sl) -> int {
        return dir ? ((t < sl) ? sl - 1 - t : t) : t;
    };

    // depth-2 register prefetch of input gates (named regs, static indexing)
    half4 gA0, gA1, gB0, gB1;
    gA0 = *(const half4*)(gA_base + (size_t)rowOf(0, slA) * 1600);
    gA1 = *(const half4*)(gA_base + (size_t)rowOf(1, slA) * 1600);
    if (vB) {
        gB0 = *(const half4*)(gB_base + (size_t)rowOf(0, slB) * 1600);
        gB1 = *(const half4*)(gB_base + (size_t)rowOf(1, slB) * 1600);
    }

    const f32x4 Cz = {0.f, 0.f, 0.f, 0.f};
    for (int t = 0; t < slmax; t++) {
        const int p = t & 1;

        // coalesced writeback of h(t-1) from hA[p]: 400 lanes x 1 dword (never drained)
        if (t > 0 && stv) {
            int tp = t - 1;
            int row = dir ? ((tp < slb_st) ? slb_st - 1 - tp : tp) : tp;
            unsigned int val = (tp < slb_st) ? *(const unsigned int*)&hA[p][m_st * 232 + 2 * u_st] : 0u;
            *(unsigned int*)(hout_base + (size_t)row * ldH) = val;
        }

        // MFMA: D = W @ h(t-1)^T  (A = W-frag, B = h-frag; D col = batch, row = 4*jh+gate)
        f32x4 C[7];
        #pragma unroll
        for (int i = 0; i < 7; i++) C[i] = Cz;
        #pragma unroll
        for (int kt = 0; kt < 7; kt++) {
            half8 hF = *(const half8*)&hA[p][l15 * 232 + kt * 32 + lq * 8];
            #pragma unroll
            for (int i = 0; i < 6; i++)
                C[i] = __builtin_amdgcn_mfma_f32_16x16x32_f16(Breg[i][kt], hF, C[i], 0, 0, 0);
            if (w < 2) {
                half8 bF = *(const half8*)&bEx[(w * 7 + kt) * 512 + l * 8];
                C[6] = __builtin_amdgcn_mfma_f32_16x16x32_f16(bF, hF, C[6], 0, 0, 0);
            }
        }

        // redistribute: active lanes (l15<4) hold 4 gates of cell (tile i, q=lq, m=l15)
        if (l15 < 4) {
            #pragma unroll
            for (int i = 0; i < 6; i++)
                *(f32x4*)&gD[w * 448 + (i * 16 + lq * 4 + l15) * 4] = C[i];
            if (w < 2)
                *(f32x4*)&gD[w * 448 + (6 * 16 + lq * 4 + l15) * 4] = C[6];
        }

        // nonlinearity on all 64 lanes (same-wave LDS, no barrier)
        {
            f32x4 gv = *(const f32x4*)&gD[w * 448 + cA * 4];
            float xi = gv[0] + (float)gA0[0];
            float xf = gv[1] + (float)gA0[1];
            float xg = gv[2] + (float)gA0[2];
            float xo = gv[3] + (float)gA0[3];
            float cn = sigm_(xf) * csA + sigm_(xi) * tanh_(xg);
            csA = cn;
            hA[1 - p][mA * 232 + hcA] = (_Float16)(sigm_(xo) * tanh_(cn));
        }
        if (vB) {
            f32x4 gv = *(const f32x4*)&gD[w * 448 + cB * 4];
            float xi = gv[0] + (float)gB0[0];
            float xf = gv[1] + (float)gB0[1];
            float xg = gv[2] + (float)gB0[2];
            float xo = gv[3] + (float)gB0[3];
            float cn = sigm_(xf) * csB + sigm_(xi) * tanh_(xg);
            csB = cn;
            hA[1 - p][mB * 232 + hcB] = (_Float16)(sigm_(xo) * tanh_(cn));
        }

        // rotate prefetch regs and issue loads for t+2 (consumed ~2 steps later)
        gA0 = gA1;
        gB0 = gB1;
        if (t + 2 < L_) {
            gA1 = *(const half4*)(gA_base + (size_t)rowOf(t + 2, slA) * 1600);
            if (vB) gB1 = *(const half4*)(gB_base + (size_t)rowOf(t + 2, slB) * 1600);
        }

        barrier_lgkm();   // LDS-only drain; vmcnt stays in flight
    }
    // epilogue 1: write back h(slmax-1) from hA[slmax&1]
    if (stv) {
        int tp = slmax - 1;
        int row = dir ? ((tp < slb_st) ? slb_st - 1 - tp : tp) : tp;
        unsigned int val = (tp < slb_st) ? *(const unsigned int*)&hA[slmax & 1][m_st * 232 + 2 * u_st] : 0u;
        *(unsigned int*)(hout_base + (size_t)row * ldH) = val;
    }
    // epilogue 2: zero-fill rows [slmax, L)
    if (stv) {
        for (int tp = slmax; tp < L_; tp++)
            *(unsigned int*)(hout_base + (size_t)tp * ldH) = 0u;
    }
}

// ---------------- logits v2 (MFMA): (B*L,18) = h1(B*L,400 f16) @ wlB^T + blog
// wlB fp16 [32][WLP] (rows >=18 and cols >=400 are zero). Per block: 64 M-rows,
// 4 waves x 16 rows; per wave 2 N-tiles (n=0..15, 16..31) x 13 K-slices = 26 MFMA.
__global__ __launch_bounds__(256) void k_logits(const _Float16* __restrict__ h1,
                                                const _Float16* __restrict__ wlB,
                                                const float* __restrict__ blog,
                                                float* __restrict__ logits) {
    __shared__ __align__(16) _Float16 sW[32 * WLP];
    const int tid = threadIdx.x;
    const int w = tid >> 6, l = tid & 63, l15 = l & 15, lq = l >> 4;
    for (int i = tid; i < 32 * WLP / 8; i += 256)
        ((half8*)sW)[i] = ((const half8*)wlB)[i];
    __syncthreads();

    const int m0 = blockIdx.x * 64 + w * 16;
    const half8 hz = {0, 0, 0, 0, 0, 0, 0, 0};
    f32x4 acc0 = {0.f, 0.f, 0.f, 0.f}, acc1 = {0.f, 0.f, 0.f, 0.f};
    const _Float16* arow = h1 + (size_t)(m0 + l15) * 400;
    #pragma unroll
    for (int kt = 0; kt < 13; kt++) {
        int col = kt * 32 + lq * 8;
        half8 aF = (col < 400) ? *(const half8*)(arow + col) : hz;
        half8 bF0 = *(const half8*)&sW[l15 * WLP + col];
        half8 bF1 = *(const half8*)&sW[(16 + l15) * WLP + col];
        acc0 = __builtin_amdgcn_mfma_f32_16x16x32_f16(aF, bF0, acc0, 0, 0, 0);
        acc1 = __builtin_amdgcn_mfma_f32_16x16x32_f16(aF, bF1, acc1, 0, 0, 0);
    }
    // D: col = l15 (n within tile), row = lq*4 + r
    {
        int n = l15;
        float bv = blog[n];   // n < 16 < NT_
        #pragma unroll
        for (int r = 0; r < 4; r++)
            logits[(size_t)(m0 + lq * 4 + r) * NT_ + n] = acc0[r] + bv;
    }
    if (16 + l15 < NT_) {
        int n = 16 + l15;
        float bv = blog[n];
        #pragma unroll
        for (int r = 0; r < 4; r++)
            logits[(size_t)(m0 + lq * 4 + r) * NT_ + n] = acc1[r] + bv;
    }
}

// ---------------- CRF NLL per batch row (54-lane-parallel LSE, single wave)
__global__ __launch_bounds__(64) void k_crf(const float* __restrict__ logits,
                                            const int* __restrict__ target,
                                            const int* __restrict__ seq_len,
                                            const float* __restrict__ trans,
                                            float* __restrict__ out) {
    int b = blockIdx.x, tid = threadIdx.x;
    __shared__ float alpha[NT_];
    int sl = seq_len[b];
    const float* lg = logits + (size_t)b * L_ * NT_;
    const int* tg = target + (size_t)b * L_;

    const bool act = tid < 54;
    const int c = tid / 18, j = tid - c * 18;

    float Tl[6];
    #pragma unroll
    for (int k = 0; k < 6; k++)
        Tl[k] = act ? trans[(6 * c + k) * NT_ + j] : 0.f;

    float gacc = 0.f;
    for (int t = tid; t < L_; t += 64) {
        if (t < sl) {
            gacc += lg[t * NT_ + tg[t]];
            if (t >= 1) gacc += trans[tg[t - 1] * NT_ + tg[t]];
        }
    }
    #pragma unroll
    for (int off = 32; off; off >>= 1) gacc += __shfl_down(gacc, off);
    float gold = __shfl(gacc, 0);

    if (tid < NT_) alpha[tid] = lg[tid];

    const int src1 = (c < 2) ? tid + 18 : tid - 36;
    const int src2 = (c == 0) ? tid + 36 : tid - 18;

    for (int t = 1; t < sl; t++) {
        float m = -1e30f, s = 0.f;
        if (act) {
            float v0 = alpha[6 * c + 0] + Tl[0];
            float v1 = alpha[6 * c + 1] + Tl[1];
            float v2 = alpha[6 * c + 2] + Tl[2];
            float v3 = alpha[6 * c + 3] + Tl[3];
            float v4 = alpha[6 * c + 4] + Tl[4];
            float v5 = alpha[6 * c + 5] + Tl[5];
            m = fmaxf(fmaxf(fmaxf(v0, v1), fmaxf(v2, v3)), fmaxf(v4, v5));
            s = __expf(v0 - m) + __expf(v1 - m) + __expf(v2 - m) +
                __expf(v3 - m) + __expf(v4 - m) + __expf(v5 - m);
        }
        float m1 = __shfl(m, src1), s1 = __shfl(s, src1);
        float m2 = __shfl(m, src2), s2 = __shfl(s, src2);
        if (act && c == 0) {
            float M = fmaxf(m, fmaxf(m1, m2));
            float S = s * __expf(m - M) + s1 * __expf(m1 - M) + s2 * __expf(m2 - M);
            alpha[j] = M + __logf(S) + lg[t * NT_ + j];
        }
    }
    if (tid == 0) {
        float mx = -1e30f;
        for (int i = 0; i < NT_; i++) mx = fmaxf(mx, alpha[i]);
        float s = 0.f;
        for (int i = 0; i < NT_; i++) s += __expf(alpha[i] - mx);
        out[b] = (mx + __logf(s)) - gold;
    }
}

extern "C" void kernel_launch(void* const* d_in, const int* in_sizes, int n_in,
                              void* d_out, int out_size, void* d_ws, size_t ws_size,
                              hipStream_t stream) {
    const int*   words  = (const int*)d_in[0];
    const int*   caps   = (const int*)d_in[1];
    const int*   seq    = (const int*)d_in[2];
    const int*   target = (const int*)d_in[3];
    const float* wemb   = (const float*)d_in[4];
    const float* cemb   = (const float*)d_in[5];
    const float* Wih0f  = (const float*)d_in[6];
    const float* Whh0f  = (const float*)d_in[7];
    const float* bih0f  = (const float*)d_in[8];
    const float* bhh0f  = (const float*)d_in[9];
    const float* Wih0b  = (const float*)d_in[10];
    const float* Whh0b  = (const float*)d_in[11];
    const float* bih0b  = (const float*)d_in[12];
    const float* bhh0b  = (const float*)d_in[13];
    const float* Wih1f  = (const float*)d_in[14];
    const float* Whh1f  = (const float*)d_in[15];
    const float* bih1f  = (const float*)d_in[16];
    const float* bhh1f  = (const float*)d_in[17];
    const float* Wih1b  = (const float*)d_in[18];
    const float* Whh1b  = (const float*)d_in[19];
    const float* bih1b  = (const float*)d_in[20];
    const float* bhh1b  = (const float*)d_in[21];
    const float* Wf     = (const float*)d_in[22];
    const float* bfv    = (const float*)d_in[23];
    const float* Wb     = (const float*)d_in[24];
    const float* bbv    = (const float*)d_in[25];
    const float* trans  = (const float*)d_in[26];

    char* base = (char*)d_ws;
    _Float16* gatesH = (_Float16*)(base + 0);                 // 104,857,600 B (32768x1600)
    _Float16* xbuf   = (_Float16*)(base + 104857600);         // 10,485,760 B (32768x160)
    _Float16* h0b    = (_Float16*)(base + 115343360);         // 27,262,976 B (32768x416)
    _Float16* h1b    = xbuf;  // 26,214,400 B needed; xbuf+h0 region dead by then
    float* logitsb   = (float*)(base + 142606336);            // 2,359,296 B
    _Float16* wihT0  = (_Float16*)(base + 144965632);         // 512,000 B (1600x160)
    _Float16* wihT1  = (_Float16*)(base + 145477632);         // 1,331,200 B (1600x416)
    float* bias0     = (float*)(base + 146808832);            // 6,400 B
    float* bias1     = (float*)(base + 146815232);            // 6,400 B
    _Float16* wlB    = (_Float16*)(base + 146821632);         // 27,136 B (32xWLP fp16)
    float* blog      = (float*)(base + 146850432);            // 128 B
    int*   permb     = (int*)(base + 146850560);              // 512 B

    // --- weight prep
    k_perm_ih16<<<(800 * KP0 + 255) / 256, 256, 0, stream>>>(Wih0f, wihT0, 130, KP0, 0);
    k_perm_ih16<<<(800 * KP0 + 255) / 256, 256, 0, stream>>>(Wih0b, wihT0, 130, KP0, 800);
    k_perm_ih16<<<(800 * KP1 + 255) / 256, 256, 0, stream>>>(Wih1f, wihT1, 400, KP1, 0);
    k_perm_ih16<<<(800 * KP1 + 255) / 256, 256, 0, stream>>>(Wih1b, wihT1, 400, KP1, 800);
    k_bias_perm<<<7, 256, 0, stream>>>(bih0f, bhh0f, bih0b, bhh0b, bias0);
    k_bias_perm<<<7, 256, 0, stream>>>(bih1f, bhh1f, bih1b, bhh1b, bias1);
    k_wlog<<<(32 * WLP + 255) / 256, 256, 0, stream>>>(Wf, bfv, Wb, bbv, wlB, blog);
    k_sortperm<<<1, 128, 0, stream>>>(seq, permb);

    // --- embeddings (fp16, padded)
    k_embed<<<B_ * L_, 128, 0, stream>>>(words, caps, wemb, cemb, xbuf);

    // zero h0 (its K-pad cols 400..415 must be 0 for the layer-1 GEMM)
    hipMemsetAsync(h0b, 0, (size_t)32768 * KP1 * sizeof(_Float16), stream);

    // --- layer 0
    k_gemm16<<<dim3(25, 256), 256, 0, stream>>>(xbuf, wihT0, bias0, gatesH, KP0);
    k_scan10<<<(B_ / SG) * 2, 512, 0, stream>>>(gatesH, Whh0f, Whh0b, seq, permb, h0b, KP1);

    // --- layer 1
    k_gemm16<<<dim3(25, 256), 256, 0, stream>>>(h0b, wihT1, bias1, gatesH, KP1);
    k_scan10<<<(B_ / SG) * 2, 512, 0, stream>>>(gatesH, Whh1f, Whh1b, seq, permb, h1b, 400);

    // --- logits + CRF
    k_logits<<<(B_ * L_) / 64, 256, 0, stream>>>(h1b, wlB, blog, logitsb);
    k_crf<<<B_, 64, 0, stream>>>(logitsb, target, seq, trans, (float*)d_out);
}